// Round 15
// baseline (167.839 us; speedup 1.0000x reference)
//
#include <hip/hip_runtime.h>
#include <hip/hip_bf16.h>

#define NNODES 50000   // must stay < 65536 (row/col packed into one u32)
#define DIM 128
#define NBUCK 196      // ceil(NNODES/256); bucket b covers rows [b*256, b*256+256)
#define BCAP 8192      // fixed segment capacity per bucket (mean 4081, sd 64 -> +64 sigma)
#define NPASS 4        // feature passes: 32 features (64B) each; 3.2MB table slice < 4MB XCD L2

typedef unsigned short u16;
typedef _Float16 f16;
typedef float  f32x4  __attribute__((ext_vector_type(4)));
typedef _Float16 f16x4v __attribute__((ext_vector_type(4)));
typedef _Float16 f16x8 __attribute__((ext_vector_type(8)));

#define MFMAH(a, b, c) __builtin_amdgcn_mfma_f32_16x16x32_f16((a), (b), (c), 0, 0, 0)

// ---------------- init: cursors (blk 0), W1->f16 (1..32), W2->f16 (33..64), zero rows (65) ----------------
__global__ __launch_bounds__(256) void init_misc(int* __restrict__ gcursor,
        const float* __restrict__ W1, const float* __restrict__ W2,
        f16* __restrict__ w1h, f16* __restrict__ w2h,
        f16* __restrict__ xs, f16* __restrict__ zs, int n) {
    int b = blockIdx.x, t = threadIdx.x;
    size_t seg = (size_t)(n + 1) * 32;
    if (b == 0) {
        gcursor[t] = t * BCAP;
    } else if (b <= 32) {
        int i = (b - 1) * 256 + t;            // 8192 quads of W1
        float4 v = reinterpret_cast<const float4*>(W1)[i];
        f16x4v o = { (f16)v.x, (f16)v.y, (f16)v.z, (f16)v.w };
        reinterpret_cast<f16x4v*>(w1h)[i] = o;
    } else if (b <= 64) {
        int i = (b - 33) * 256 + t;           // 8192 quads of W2
        float4 v = reinterpret_cast<const float4*>(W2)[i];
        f16x4v o = { (f16)v.x, (f16)v.y, (f16)v.z, (f16)v.w };
        reinterpret_cast<f16x4v*>(w2h)[i] = o;
    } else {
        // zero row N of each pass region of xs (t<32) and zs (32<=t<64)
        f16x4v o = {};
        if (t < 32) {
            int p = t >> 3, l = t & 7;
            reinterpret_cast<f16x4v*>(xs + (size_t)p * seg)[(size_t)n * 8 + l] = o;
        } else if (t < 64) {
            int tt = t - 32;
            int p = tt >> 3, l = tt & 7;
            reinterpret_cast<f16x4v*>(zs + (size_t)p * seg)[(size_t)n * 8 + l] = o;
        }
    }
}

// ---------------- pass B: place packed (row,col) edges into fixed bucket segments ----------------
__global__ __launch_bounds__(256) void bucket_place(const int* __restrict__ row,
                                                    const int* __restrict__ col,
                                                    int* __restrict__ gcursor,
                                                    unsigned* __restrict__ bkt, int nE) {
    __shared__ int hist[256];
    __shared__ int cur[256];
    int t = threadIdx.x;
    hist[t] = 0;
    __syncthreads();
    unsigned pk[8]; int valid = 0;
    int base_e = blockIdx.x * 2048 + t;
    #pragma unroll
    for (int k = 0; k < 8; ++k) {
        int e = base_e + k * 256;
        if (e < nE) {
            unsigned r = (unsigned)row[e], c = (unsigned)col[e];
            pk[k] = (r << 16) | c;
            valid |= 1 << k;
            atomicAdd(&hist[r >> 8], 1);
        }
    }
    __syncthreads();
    if (hist[t] > 0) cur[t] = atomicAdd(&gcursor[t], hist[t]);
    __syncthreads();
    #pragma unroll
    for (int k = 0; k < 8; ++k) {
        if (valid & (1 << k)) {
            int pos = atomicAdd(&cur[pk[k] >> 24], 1);   // pk>>24 == row>>8
            bkt[pos] = pk[k];
        }
    }
}

// ---------------- pass C: per bucket -> row ranges, dinv, cols16, pass-blocked xs ----------------
__global__ __launch_bounds__(256) void csr_fill(const unsigned* __restrict__ bkt,
                                                const int* __restrict__ gcursor,
                                                const float* __restrict__ x,
                                                int2* __restrict__ row_rng,
                                                float* __restrict__ dinv,
                                                u16* __restrict__ cols16,
                                                f16* __restrict__ xs, int n) {
    __shared__ int lcnt[256], lscan[256], lcur[256];
    __shared__ float ldinv[256];
    int b = blockIdx.x, t = threadIdx.x;
    int r0 = b << 8;
    int s = b * BCAP, e = gcursor[b];
    size_t seg = (size_t)(n + 1) * 32;
    lcnt[t] = 0;
    __syncthreads();
    for (int i = s + t; i < e; i += 256)
        atomicAdd(&lcnt[(bkt[i] >> 16) & 255], 1);
    __syncthreads();
    int v = lcnt[t];
    lscan[t] = v;
    __syncthreads();
    for (int off = 1; off < 256; off <<= 1) {
        int u = (t >= off) ? lscan[t - off] : 0;
        __syncthreads();
        lscan[t] += u;
        __syncthreads();
    }
    int gpos = s + lscan[t] - v;              // exclusive prefix within segment
    int r = r0 + t;
    float dval = rsqrtf((float)(v + 1));      // +1 self loop; deg>=1 so clip no-op
    ldinv[t] = dval;
    if (r < n) {
        row_rng[r] = make_int2(gpos, gpos + v);
        dinv[r] = dval;
    }
    lcur[t] = gpos;
    __syncthreads();
    for (int i = s + t; i < e; i += 256) {
        unsigned rc = bkt[i];
        int pos = atomicAdd(&lcur[(rc >> 16) & 255], 1);
        cols16[pos] = (u16)(rc & 0xffffu);
    }
    // xs = dinv (.) x, pass-blocked layout xs[p][(row)][32]
    int nrows = min(256, n - r0);
    if (nrows > 0) {
        int totq = nrows * 32;
        for (int q = t; q < totq; q += 256) {
            int rl = q >> 5;
            int qq = q & 31;                  // quad within row (0..31)
            int p = qq >> 3, l = qq & 7;
            float d = ldinv[rl];
            float4 vx = reinterpret_cast<const float4*>(x)[(size_t)(r0 + rl) * 32 + qq];
            f16x4v o = { (f16)(d * vx.x), (f16)(d * vx.y), (f16)(d * vx.z), (f16)(d * vx.w) };
            reinterpret_cast<f16x4v*>(xs + (size_t)p * seg)[(size_t)(r0 + rl) * 8 + l] = o;
        }
    }
}

// ---------------- pass-blocked SPMM: 4 feature passes, 3.2MB L2-resident slice each ----------------
// All ~1563 blocks co-resident (<=64 VGPR) -> passes phase-aligned machine-wide.
// Y[i,:] = dinv[i] * ( Xs[i,:] + sum_j Xs[c_j,:] )  (+ bias)
template <bool OUT16, bool BIAS>
__global__ __launch_bounds__(256, 8) void spmm_pass(const int2* __restrict__ row_rng,
                         const u16* __restrict__ cols16,
                         const f16* __restrict__ Xb, const float* __restrict__ dinv,
                         const float* __restrict__ bias,
                         float* __restrict__ Y, f16* __restrict__ Yb, int n) {
    int tid = blockIdx.x * 256 + threadIdx.x;
    int i = tid >> 3;        // node (32 nodes per block)
    int l = tid & 7;         // 8B slot within the 32-feature pass chunk
    if (i >= n) return;
    int2 rng = row_rng[i];
    float di = dinv[i];
    size_t seg = (size_t)(n + 1) * 32;
    #pragma unroll 1
    for (int p = 0; p < NPASS; ++p) {
        const f16x4v* X4 = reinterpret_cast<const f16x4v*>(Xb + (size_t)p * seg);
        f16x4v xv = X4[(size_t)i * 8 + l];        // self term (pre-scaled)
        float4 acc;
        acc.x = (float)xv[0]; acc.y = (float)xv[1];
        acc.z = (float)xv[2]; acc.w = (float)xv[3];
        int s = rng.x, e = rng.y;
        for (int j = s; j < e; j += 8) {
            int c[8];
            #pragma unroll
            for (int t = 0; t < 8; ++t) {
                int idx = j + t;
                bool ok = idx < e;
                int cc = (int)cols16[ok ? idx : (e - 1)];
                c[t] = ok ? cc : n;               // invalid -> zero row N
            }
            f16x4v g[8];
            #pragma unroll
            for (int t = 0; t < 8; ++t) g[t] = X4[(size_t)c[t] * 8 + l];  // 64B row-slice gathers
            #pragma unroll
            for (int t = 0; t < 8; ++t) {
                acc.x += (float)g[t][0];
                acc.y += (float)g[t][1];
                acc.z += (float)g[t][2];
                acc.w += (float)g[t][3];
            }
        }
        acc.x *= di; acc.y *= di; acc.z *= di; acc.w *= di;
        if (BIAS) {
            float4 bb = reinterpret_cast<const float4*>(bias)[p * 8 + l];
            acc.x += bb.x; acc.y += bb.y; acc.z += bb.z; acc.w += bb.w;
        }
        if (OUT16) {
            f16x4v o = { (f16)acc.x, (f16)acc.y, (f16)acc.z, (f16)acc.w };
            reinterpret_cast<f16x4v*>(Yb + (size_t)p * seg)[(size_t)i * 8 + l] = o;
        } else {
            reinterpret_cast<float4*>(Y)[(size_t)i * 32 + p * 8 + l] = acc;
        }
    }
}

// ---------------- fused MLP: zs = dinv (.) [ relu(y1 W1^T + b1) W2^T ], all f16 MFMA ----------------
// y1 and zs are pass-blocked [p][(N+1)][32]; y1's ks-chunks align exactly with passes.
__global__ __launch_bounds__(256, 2) void mlp_fused(
        const f16* __restrict__ y1, const f16* __restrict__ w1,
        const float* __restrict__ b1, const f16* __restrict__ w2,
        const float* __restrict__ dinv, f16* __restrict__ zs, int M) {
    constexpr int HSTR = 264;                 // 256 + 8 pad: 16B-aligned rows
    __shared__ f16 hl[4][32][HSTR];           // 66 KB -> 2 blocks/CU
    const int wave = threadIdx.x >> 6;
    const int lane = threadIdx.x & 63;
    const int lr = lane & 15;
    const int lq = lane >> 4;
    const int mbase = blockIdx.x * 128 + wave * 32;
    const size_t seg = (size_t)(M + 1) * 32;

    f16x8 yb[2][4];
    #pragma unroll
    for (int nf = 0; nf < 2; ++nf) {
        int r = min(mbase + nf * 16 + lr, M - 1);
        #pragma unroll
        for (int ks = 0; ks < 4; ++ks)
            yb[nf][ks] = *reinterpret_cast<const f16x8*>(y1 + (size_t)ks * seg + (size_t)r * 32 + lq * 8);
    }

    #pragma unroll 1
    for (int q = 0; q < 4; ++q) {
        const int hc0 = q * 64;
        f16x8 wa[4][4];
        #pragma unroll
        for (int mf = 0; mf < 4; ++mf) {
            const f16* pw = w1 + (size_t)(hc0 + mf * 16 + lr) * 128 + lq * 8;
            #pragma unroll
            for (int ks = 0; ks < 4; ++ks)
                wa[mf][ks] = *reinterpret_cast<const f16x8*>(pw + ks * 32);
        }
        f32x4 acc[4][2] = {};
        #pragma unroll
        for (int ks = 0; ks < 4; ++ks)
            #pragma unroll
            for (int mf = 0; mf < 4; ++mf)
                #pragma unroll
                for (int nf = 0; nf < 2; ++nf)
                    acc[mf][nf] = MFMAH(wa[mf][ks], yb[nf][ks], acc[mf][nf]);
        #pragma unroll
        for (int mf = 0; mf < 4; ++mf) {
            float4 bb = *reinterpret_cast<const float4*>(&b1[hc0 + mf * 16 + lq * 4]);
            #pragma unroll
            for (int nf = 0; nf < 2; ++nf) {
                f16x4v hv = { (f16)fmaxf(acc[mf][nf][0] + bb.x, 0.f),
                              (f16)fmaxf(acc[mf][nf][1] + bb.y, 0.f),
                              (f16)fmaxf(acc[mf][nf][2] + bb.z, 0.f),
                              (f16)fmaxf(acc[mf][nf][3] + bb.w, 0.f) };
                *reinterpret_cast<f16x4v*>(&hl[wave][nf * 16 + lr][hc0 + mf * 16 + lq * 4]) = hv;
            }
        }
    }

    f32x4 acc2[8][2] = {};
    #pragma unroll 1
    for (int ks = 0; ks < 8; ++ks) {
        f16x8 hb[2];
        #pragma unroll
        for (int nf = 0; nf < 2; ++nf)
            hb[nf] = *reinterpret_cast<const f16x8*>(&hl[wave][nf * 16 + lr][ks * 32 + lq * 8]);
        f16x8 wa2[8];
        #pragma unroll
        for (int mf = 0; mf < 8; ++mf)
            wa2[mf] = *reinterpret_cast<const f16x8*>(w2 + (size_t)(mf * 16 + lr) * 256 + ks * 32 + lq * 8);
        #pragma unroll
        for (int mf = 0; mf < 8; ++mf)
            #pragma unroll
            for (int nf = 0; nf < 2; ++nf)
                acc2[mf][nf] = MFMAH(wa2[mf], hb[nf], acc2[mf][nf]);
    }
    #pragma unroll
    for (int nf = 0; nf < 2; ++nf) {
        int node = mbase + nf * 16 + lr;
        if (node >= M) continue;
        float dn = dinv[node];
        #pragma unroll
        for (int mf = 0; mf < 8; ++mf) {
            // feature f0 = mf*16 + lq*4 -> pass p = mf>>1, quad (mf&1)*4 + lq
            int p = mf >> 1;
            int qd = (mf & 1) * 4 + lq;
            f16x4v zv = { (f16)(dn * acc2[mf][nf][0]), (f16)(dn * acc2[mf][nf][1]),
                          (f16)(dn * acc2[mf][nf][2]), (f16)(dn * acc2[mf][nf][3]) };
            reinterpret_cast<f16x4v*>(zs + (size_t)p * seg)[(size_t)node * 8 + qd] = zv;
        }
    }
}

extern "C" void kernel_launch(void* const* d_in, const int* in_sizes, int n_in,
                              void* d_out, int out_size, void* d_ws, size_t ws_size,
                              hipStream_t stream) {
    const float* x  = (const float*)d_in[0];
    const int*   ei = (const int*)d_in[1];
    const float* W1 = (const float*)d_in[2];
    const float* b1 = (const float*)d_in[3];
    const float* W2 = (const float*)d_in[4];
    const float* b2 = (const float*)d_in[5];
    float* out = (float*)d_out;

    const int N = NNODES;
    const int E = in_sizes[1] / 2;
    const int IN_D = 128, HID = 256;
    const int* row = ei;
    const int* col = ei + E;

    // workspace carve-out (aligned to 256B)
    char* ws = (char*)d_ws;
    size_t off = 0;
    auto carve = [&](size_t bytes) { void* p = ws + off; off += (bytes + 255) & ~size_t(255); return p; };
    int*      gcursor = (int*)carve((size_t)256 * 4);
    int2*     row_rng = (int2*)carve((size_t)N * 8);
    float*    dinv    = (float*)carve((size_t)N * 4);
    unsigned* bkt     = (unsigned*)carve((size_t)NBUCK * BCAP * 4); // segmented (row<<16|col)
    u16*      cols16  = (u16*)carve((size_t)NBUCK * BCAP * 2);
    f16*      w1h     = (f16*)carve((size_t)HID * IN_D * 2);
    f16*      w2h     = (f16*)carve((size_t)IN_D * HID * 2);
    f16*      xs      = (f16*)carve((size_t)NPASS * (N + 1) * 32 * 2); // pass-blocked, +zero row
    f16*      y1h     = (f16*)carve((size_t)NPASS * (N + 1) * 32 * 2); // pass-blocked, becomes zs
    f16*      zsh     = y1h;

    const int TB = 256;
    const int eblk = (E + 2047) / 2048;   // 391

    // 1) init -> place -> fill (+dinv +blocked xs)
    init_misc<<<66, TB, 0, stream>>>(gcursor, W1, W2, w1h, w2h, xs, zsh, N);
    bucket_place<<<eblk, TB, 0, stream>>>(row, col, gcursor, bkt, E);
    csr_fill<<<NBUCK, TB, 0, stream>>>(bkt, gcursor, x, row_rng, dinv, cols16, xs, N);

    // 2) y1 = A' x   (4 feature passes, L2-resident slice -> f16 blocked out)
    spmm_pass<true, false><<<(N * 8 + TB - 1) / TB, TB, 0, stream>>>(
        row_rng, cols16, xs, dinv, nullptr, nullptr, y1h, N);

    // 3) zs = dinv (.) [ relu(y1 W1^T + b1) W2^T ]   (fused, blocked in/out, in-place)
    mlp_fused<<<(N + 127) / 128, 256, 0, stream>>>(y1h, w1h, b1, w2h, dinv, zsh, N);

    // 4) out = A' z + b2   (4 feature passes -> fp32 row-major out)
    spmm_pass<false, true><<<(N * 8 + TB - 1) / TB, TB, 0, stream>>>(
        row_rng, cols16, zsh, dinv, b2, out, nullptr, N);
}

// Round 16
// 143.655 us; speedup vs baseline: 1.1684x; 1.1684x over previous
//
#include <hip/hip_runtime.h>
#include <hip/hip_bf16.h>

#define NNODES 50000   // must stay < 65536 (row/col packed into one u32)
#define DIM 128        // both SPMMs run on 128 dims after the W2 reorder
#define NBUCK 196      // ceil(NNODES/256); bucket b covers rows [b*256, b*256+256)
#define BCAP 8192      // fixed segment capacity per bucket (mean 4081, sd 64 -> +64 sigma)

typedef unsigned short u16;
typedef _Float16 f16;
typedef float  f32x4  __attribute__((ext_vector_type(4)));
typedef _Float16 f16x4v __attribute__((ext_vector_type(4)));
typedef _Float16 f16x8 __attribute__((ext_vector_type(8)));

#define MFMAH(a, b, c) __builtin_amdgcn_mfma_f32_16x16x32_f16((a), (b), (c), 0, 0, 0)

// ---------------- cursor init: cursor[b] = b*BCAP ----------------
__global__ void init_cursor(int* __restrict__ cursor) {
    cursor[threadIdx.x] = (int)threadIdx.x * BCAP;
}

// ---------------- pass B: place packed (row,col) edges into fixed bucket segments ----------------
// LDS-batched: one global atomicAdd per (block,bucket) touched; per-(block,bucket)
// runs are contiguous (~80B store runs instead of random 4B).
__global__ __launch_bounds__(256) void bucket_place(const int* __restrict__ row,
                                                    const int* __restrict__ col,
                                                    int* __restrict__ gcursor,
                                                    unsigned* __restrict__ bkt, int nE) {
    __shared__ int hist[256];
    __shared__ int cur[256];
    int t = threadIdx.x;
    hist[t] = 0;
    __syncthreads();
    unsigned pk[8]; int valid = 0;
    int base_e = blockIdx.x * 2048 + t;
    #pragma unroll
    for (int k = 0; k < 8; ++k) {
        int e = base_e + k * 256;
        if (e < nE) {
            unsigned r = (unsigned)row[e], c = (unsigned)col[e];
            pk[k] = (r << 16) | c;
            valid |= 1 << k;
            atomicAdd(&hist[r >> 8], 1);
        }
    }
    __syncthreads();
    if (hist[t] > 0) cur[t] = atomicAdd(&gcursor[t], hist[t]);
    __syncthreads();
    #pragma unroll
    for (int k = 0; k < 8; ++k) {
        if (valid & (1 << k)) {
            int pos = atomicAdd(&cur[pk[k] >> 24], 1);   // pk>>24 == row>>8
            bkt[pos] = pk[k];
        }
    }
}

// ---------------- pass C: one block per bucket -> row ranges (int2), dinv, cols16 ----------------
// Segmented CSR: cols for bucket b live in [b*BCAP, gcursor[b]); per-row range from
// intra-bucket count+scan. No compact global scan needed.
__global__ __launch_bounds__(256) void csr_fill(const unsigned* __restrict__ bkt,
                                                const int* __restrict__ gcursor,
                                                int2* __restrict__ row_rng,
                                                float* __restrict__ dinv,
                                                u16* __restrict__ cols16, int n) {
    __shared__ int lcnt[256], lscan[256], lcur[256];
    int b = blockIdx.x, t = threadIdx.x;
    int r0 = b << 8;
    int s = b * BCAP, e = gcursor[b];
    lcnt[t] = 0;
    __syncthreads();
    for (int i = s + t; i < e; i += 256)
        atomicAdd(&lcnt[(bkt[i] >> 16) & 255], 1);
    __syncthreads();
    int v = lcnt[t];
    lscan[t] = v;
    __syncthreads();
    for (int off = 1; off < 256; off <<= 1) {
        int u = (t >= off) ? lscan[t - off] : 0;
        __syncthreads();
        lscan[t] += u;
        __syncthreads();
    }
    int gpos = s + lscan[t] - v;          // exclusive prefix within segment
    int r = r0 + t;
    if (r < n) {
        row_rng[r] = make_int2(gpos, gpos + v);
        dinv[r] = rsqrtf((float)(v + 1)); // +1 self loop; deg>=1 so clip no-op
    }
    lcur[t] = gpos;
    __syncthreads();
    for (int i = s + t; i < e; i += 256) {
        unsigned rc = bkt[i];
        int pos = atomicAdd(&lcur[(rc >> 16) & 255], 1);
        cols16[pos] = (u16)(rc & 0xffffu);
    }
}

// ---------------- prep: W1/W2 -> f16, xs = dinv*x (f16), zero rows N of xs/zs ----------------
__global__ __launch_bounds__(256) void prep_tables(
        const float* __restrict__ W1, const float* __restrict__ W2,
        const float* __restrict__ x, const float* __restrict__ dinv,
        f16* __restrict__ w1h, f16* __restrict__ w2h,
        f16* __restrict__ xs, f16* __restrict__ zs, int n) {
    const int WQ = (256 * 128) / 4;       // 8192 quads per weight
    const int XQ = n * (DIM / 4);         // node-feature quads
    int i = blockIdx.x * 256 + threadIdx.x;
    if (i < WQ) {
        float4 v = reinterpret_cast<const float4*>(W1)[i];
        f16x4v o = { (f16)v.x, (f16)v.y, (f16)v.z, (f16)v.w };
        reinterpret_cast<f16x4v*>(w1h)[i] = o;
    } else if (i < 2 * WQ) {
        int j = i - WQ;
        float4 v = reinterpret_cast<const float4*>(W2)[j];
        f16x4v o = { (f16)v.x, (f16)v.y, (f16)v.z, (f16)v.w };
        reinterpret_cast<f16x4v*>(w2h)[j] = o;
    } else {
        int j = i - 2 * WQ;
        if (j < XQ) {
            float d = dinv[j >> 5];
            float4 v = reinterpret_cast<const float4*>(x)[j];
            f16x4v o = { (f16)(d * v.x), (f16)(d * v.y), (f16)(d * v.z), (f16)(d * v.w) };
            reinterpret_cast<f16x4v*>(xs)[j] = o;
        } else if (j < XQ + 32) {          // zero row N of xs (gather tail target)
            f16x4v o = {};
            reinterpret_cast<f16x4v*>(xs)[j] = o;
        } else if (j < XQ + 64) {          // zero row N of zs
            f16x4v o = {};
            reinterpret_cast<f16x4v*>(zs)[XQ + (j - XQ - 32)] = o;
        }
    }
}

// ---------------- CSR SPMM: pre-scaled f16 gather, batched-16, zero-row tail ----------------
// Y[i,:] = dinv[i] * ( Xs[i,:] + sum_j Xs[c_j,:] )  (+ bias)   where Xs = dinv (.) X
template <bool OUT16, bool BIAS>
__global__ __launch_bounds__(256) void spmm_gather(const int2* __restrict__ row_rng,
                         const u16* __restrict__ cols16,
                         const f16* __restrict__ Xs, const float* __restrict__ dinv,
                         const float* __restrict__ bias,
                         float* __restrict__ Y, f16* __restrict__ Yh, int n) {
    int tid = blockIdx.x * blockDim.x + threadIdx.x;
    int i = tid >> 5;        // node
    int l = tid & 31;        // 4-elem slot (DIM/4 == 32)
    if (i >= n) return;
    const f16x4v* X4 = reinterpret_cast<const f16x4v*>(Xs);
    int2 rng = row_rng[i];
    float di = dinv[i];
    f16x4v xv = X4[(size_t)i * 32 + l];           // self term (pre-scaled)
    float4 acc;
    acc.x = (float)xv[0]; acc.y = (float)xv[1];
    acc.z = (float)xv[2]; acc.w = (float)xv[3];
    int s = rng.x, e = rng.y;
    for (int j = s; j < e; j += 16) {
        int c[16];
        #pragma unroll
        for (int t = 0; t < 16; ++t) {
            int idx = j + t;
            bool ok = idx < e;
            int cc = (int)cols16[ok ? idx : (e - 1)];
            c[t] = ok ? cc : n;                   // invalid -> zero row N
        }
        f16x4v g[16];
        #pragma unroll
        for (int t = 0; t < 16; ++t) g[t] = X4[(size_t)c[t] * 32 + l];  // 32 in flight/wave
        #pragma unroll
        for (int t = 0; t < 16; ++t) {
            acc.x += (float)g[t][0];
            acc.y += (float)g[t][1];
            acc.z += (float)g[t][2];
            acc.w += (float)g[t][3];
        }
    }
    acc.x *= di; acc.y *= di; acc.z *= di; acc.w *= di;
    if (BIAS) {
        float4 b = reinterpret_cast<const float4*>(bias)[l];
        acc.x += b.x; acc.y += b.y; acc.z += b.z; acc.w += b.w;
    }
    if (OUT16) {
        f16x4v o = { (f16)acc.x, (f16)acc.y, (f16)acc.z, (f16)acc.w };
        *reinterpret_cast<f16x4v*>(&Yh[(size_t)i * DIM + l * 4]) = o;
    } else {
        reinterpret_cast<float4*>(Y)[(size_t)i * 32 + l] = acc;
    }
}

// ---------------- fused MLP: zs = dinv (.) [ relu(y1 W1^T + b1) W2^T ], all f16 MFMA ----------------
// Barrier-free: each wave owns 32 rows end-to-end; h lives in wave-private LDS.
__global__ __launch_bounds__(256, 2) void mlp_fused(
        const f16* __restrict__ y1, const f16* __restrict__ w1,
        const float* __restrict__ b1, const f16* __restrict__ w2,
        const float* __restrict__ dinv, f16* __restrict__ zs, int M) {
    constexpr int HSTR = 264;                 // 256 + 8 pad: 16B-aligned rows
    __shared__ f16 hl[4][32][HSTR];           // 66 KB -> 2 blocks/CU
    const int wave = threadIdx.x >> 6;
    const int lane = threadIdx.x & 63;
    const int lr = lane & 15;                 // fragment row/col index
    const int lq = lane >> 4;                 // k-quad (8 elems)
    const int mbase = blockIdx.x * 128 + wave * 32;

    // y1 B-frags for this wave's 32 rows, all k=128: read once, reuse all quarters.
    f16x8 yb[2][4];
    #pragma unroll
    for (int nf = 0; nf < 2; ++nf) {
        int r = min(mbase + nf * 16 + lr, M - 1);
        const f16* pr = y1 + (size_t)r * 128 + lq * 8;
        #pragma unroll
        for (int ks = 0; ks < 4; ++ks)
            yb[nf][ks] = *reinterpret_cast<const f16x8*>(pr + ks * 32);
    }

    // ---- phase 1: h = relu(y1 W1^T + b1), 4 quarters of 64 h-cols ----
    #pragma unroll 1
    for (int q = 0; q < 4; ++q) {
        const int hc0 = q * 64;
        f16x8 wa[4][4];
        #pragma unroll
        for (int mf = 0; mf < 4; ++mf) {
            const f16* pw = w1 + (size_t)(hc0 + mf * 16 + lr) * 128 + lq * 8;
            #pragma unroll
            for (int ks = 0; ks < 4; ++ks)
                wa[mf][ks] = *reinterpret_cast<const f16x8*>(pw + ks * 32);
        }
        f32x4 acc[4][2] = {};
        #pragma unroll
        for (int ks = 0; ks < 4; ++ks)
            #pragma unroll
            for (int mf = 0; mf < 4; ++mf)
                #pragma unroll
                for (int nf = 0; nf < 2; ++nf)
                    acc[mf][nf] = MFMAH(wa[mf][ks], yb[nf][ks], acc[mf][nf]);
        #pragma unroll
        for (int mf = 0; mf < 4; ++mf) {
            float4 bb = *reinterpret_cast<const float4*>(&b1[hc0 + mf * 16 + lq * 4]);
            #pragma unroll
            for (int nf = 0; nf < 2; ++nf) {
                f16x4v hv = { (f16)fmaxf(acc[mf][nf][0] + bb.x, 0.f),
                              (f16)fmaxf(acc[mf][nf][1] + bb.y, 0.f),
                              (f16)fmaxf(acc[mf][nf][2] + bb.z, 0.f),
                              (f16)fmaxf(acc[mf][nf][3] + bb.w, 0.f) };
                *reinterpret_cast<f16x4v*>(&hl[wave][nf * 16 + lr][hc0 + mf * 16 + lq * 4]) = hv;
            }
        }
    }

    // ---- phase 2: z = h W2^T  (wave-private LDS reads; no barrier needed) ----
    f32x4 acc2[8][2] = {};
    #pragma unroll 1
    for (int ks = 0; ks < 8; ++ks) {
        f16x8 hb[2];
        #pragma unroll
        for (int nf = 0; nf < 2; ++nf)
            hb[nf] = *reinterpret_cast<const f16x8*>(&hl[wave][nf * 16 + lr][ks * 32 + lq * 8]);
        f16x8 wa2[8];
        #pragma unroll
        for (int mf = 0; mf < 8; ++mf)
            wa2[mf] = *reinterpret_cast<const f16x8*>(w2 + (size_t)(mf * 16 + lr) * 256 + ks * 32 + lq * 8);
        #pragma unroll
        for (int mf = 0; mf < 8; ++mf)
            #pragma unroll
            for (int nf = 0; nf < 2; ++nf)
                acc2[mf][nf] = MFMAH(wa2[mf], hb[nf], acc2[mf][nf]);
    }
    #pragma unroll
    for (int nf = 0; nf < 2; ++nf) {
        int node = mbase + nf * 16 + lr;
        if (node >= M) continue;
        float dn = dinv[node];
        #pragma unroll
        for (int mf = 0; mf < 8; ++mf) {
            f16x4v zv = { (f16)(dn * acc2[mf][nf][0]), (f16)(dn * acc2[mf][nf][1]),
                          (f16)(dn * acc2[mf][nf][2]), (f16)(dn * acc2[mf][nf][3]) };
            *reinterpret_cast<f16x4v*>(zs + (size_t)node * 128 + mf * 16 + lq * 4) = zv;
        }
    }
}

extern "C" void kernel_launch(void* const* d_in, const int* in_sizes, int n_in,
                              void* d_out, int out_size, void* d_ws, size_t ws_size,
                              hipStream_t stream) {
    const float* x  = (const float*)d_in[0];
    const int*   ei = (const int*)d_in[1];
    const float* W1 = (const float*)d_in[2];
    const float* b1 = (const float*)d_in[3];
    const float* W2 = (const float*)d_in[4];
    const float* b2 = (const float*)d_in[5];
    float* out = (float*)d_out;

    const int N = NNODES;
    const int E = in_sizes[1] / 2;
    const int IN_D = 128, HID = 256;
    const int* row = ei;
    const int* col = ei + E;

    // workspace carve-out (aligned to 256B)
    char* ws = (char*)d_ws;
    size_t off = 0;
    auto carve = [&](size_t bytes) { void* p = ws + off; off += (bytes + 255) & ~size_t(255); return p; };
    int*      gcursor = (int*)carve((size_t)256 * 4);
    int2*     row_rng = (int2*)carve((size_t)N * 8);
    float*    dinv    = (float*)carve((size_t)N * 4);
    unsigned* bkt     = (unsigned*)carve((size_t)NBUCK * BCAP * 4); // segmented (row<<16|col)
    u16*      cols16  = (u16*)carve((size_t)NBUCK * BCAP * 2);      // segmented cols
    f16*      w1h     = (f16*)carve((size_t)HID * IN_D * 2);
    f16*      w2h     = (f16*)carve((size_t)IN_D * HID * 2);
    f16*      xs      = (f16*)carve((size_t)(N + 1) * IN_D * 2); // pre-scaled x, +zero row
    f16*      y1h     = (f16*)carve((size_t)(N + 1) * IN_D * 2); // y1, becomes zs in-place (+zero row)
    f16*      zsh     = y1h;

    const int TB = 256;
    const int eblk = (E + 2047) / 2048;   // 391

    // 1) segmented CSR build: init cursors -> place -> fill (no hist, no scan)
    init_cursor<<<1, 256, 0, stream>>>(gcursor);
    bucket_place<<<eblk, TB, 0, stream>>>(row, col, gcursor, bkt, E);
    csr_fill<<<NBUCK, TB, 0, stream>>>(bkt, gcursor, row_rng, dinv, cols16, N);

    // 2) prep: weights->f16, xs = dinv(.)x, zero tail rows (needs dinv)
    {
        int total_q = 2 * (HID * IN_D / 4) + N * (DIM / 4) + 64;
        prep_tables<<<(total_q + TB - 1) / TB, TB, 0, stream>>>(
            W1, W2, x, dinv, w1h, w2h, xs, zsh, N);
    }

    // 3) y1 = A' x   (pure gather+add -> f16 out)
    spmm_gather<true, false><<<(N * 32 + TB - 1) / TB, TB, 0, stream>>>(
        row_rng, cols16, xs, dinv, nullptr, nullptr, y1h, N);

    // 4) zs = dinv (.) [ relu(y1 W1^T + b1) W2^T ]   (fused, in-place over y1)
    mlp_fused<<<(N + 127) / 128, 256, 0, stream>>>(y1h, w1h, b1, w2h, dinv, zsh, N);

    // 5) out = A' z + b2 = dinv (.) (zs_self + sum zs_c) + b2   (fp32 out)
    spmm_gather<false, true><<<(N * 32 + TB - 1) / TB, TB, 0, stream>>>(
        row_rng, cols16, zsh, dinv, b2, out, nullptr, N);
}